// Round 7
// baseline (447.107 us; speedup 1.0000x reference)
//
#include <hip/hip_runtime.h>
#include <cstdint>
#include <cstddef>

typedef unsigned short u16;
typedef unsigned int u32;
typedef short s16x8 __attribute__((ext_vector_type(8)));
typedef float f32x4 __attribute__((ext_vector_type(4)));
typedef _Float16 f16x2 __attribute__((ext_vector_type(2)));

__device__ __forceinline__ float fdot2(f16x2 a, f16x2 b, float c) {
#if defined(__HIP_DEVICE_COMPILE__) && __has_builtin(__builtin_amdgcn_fdot2)
  return __builtin_amdgcn_fdot2(a, b, c, false);
#else
  return (float)a.x * (float)b.x + (float)a.y * (float)b.y + c;
#endif
}

// sum across the 8 lanes of an entry group — DPP-fused adds (1 instr/stage)
__device__ __forceinline__ float red8(float x) {
#if defined(__HIP_DEVICE_COMPILE__)
  asm("v_add_f32_dpp %0, %0, %0 quad_perm:[1,0,3,2] row_mask:0xf bank_mask:0xf"
      : "+v"(x));
  asm("v_add_f32_dpp %0, %0, %0 quad_perm:[2,3,0,1] row_mask:0xf bank_mask:0xf"
      : "+v"(x));
  asm("v_add_f32_dpp %0, %0, %0 row_half_mirror row_mask:0xf bank_mask:0xf"
      : "+v"(x));
  return x;
#else
  x += __shfl_xor(x, 1); x += __shfl_xor(x, 2); x += __shfl_xor(x, 4);
  return x;
#endif
}

// acc += f16(lo/hi of hv) * p   — single v_fma_mix_f32 each
__device__ __forceinline__ void fmamix_lo(float& a, u32 hv, float p) {
#if defined(__HIP_DEVICE_COMPILE__)
  asm("v_fma_mix_f32 %0, %1, %2, %0 op_sel_hi:[1,0,0]"
      : "+v"(a) : "v"(hv), "v"(p));
#else
  union { u32 i; _Float16 h[2]; } c; c.i = hv; a += (float)c.h[0] * p;
#endif
}
__device__ __forceinline__ void fmamix_hi(float& a, u32 hv, float p) {
#if defined(__HIP_DEVICE_COMPILE__)
  asm("v_fma_mix_f32 %0, %1, %2, %0 op_sel:[1,0,0] op_sel_hi:[1,0,0]"
      : "+v"(a) : "v"(hv), "v"(p));
#else
  union { u32 i; _Float16 h[2]; } c; c.i = hv; a += (float)c.h[1] * p;
#endif
}

#define S_LEN 2048
#define EMB   1024
#define NHEAD 16
#define HD    64
#define E3    3072
#define MLPD  4096
#define NROWS 4096   // B*S
#define LCAP  640    // max kept cols per block-row (mean ~205, sd ~14)

__device__ __forceinline__ float bf2f(u16 v) {
  union { u32 i; float f; } c; c.i = ((u32)v) << 16; return c.f;
}
__device__ __forceinline__ u16 f2bf(float f) {
  union { float f; u32 i; } c; c.f = f;
  u32 x = c.i;
  return (u16)((x + 0x7FFFu + ((x >> 16) & 1u)) >> 16);
}
__device__ __forceinline__ u16 f2h(float f) {
  _Float16 h = (_Float16)f;
  union { _Float16 h; u16 b; } c; c.h = h; return c.b;
}

__device__ __forceinline__ void gl2lds16(const void* g, void* l) {
  __builtin_amdgcn_global_load_lds(
      (__attribute__((address_space(1))) void*)(g),
      (__attribute__((address_space(3))) void*)(l), 16, 0, 0);
}

// ---------------- dtype + mask-representation detection ----------------
__global__ void detect_flags(const u32* __restrict__ w1s, int* __restrict__ dtflag,
                             const u32* __restrict__ mask, int* __restrict__ maskrep) {
  __shared__ int hits[256];
  __shared__ u32 red[256];
  int h = 0; u32 v = 0;
  for (int i = threadIdx.x; i < 4096; i += 256) {
    u32 w = w1s[i];
    if ((w & 0xFFFFu) && (((w >> 7) & 0xFFu) >= 0xC8u)) ++h;
    v |= mask[i];
  }
  hits[threadIdx.x] = h; red[threadIdx.x] = v;
  __syncthreads();
  if (threadIdx.x == 0) {
    int t = 0; u32 o = 0;
    for (int i = 0; i < 256; ++i) { t += hits[i]; o |= red[i]; }
    *dtflag = (t > 8) ? 1 : 0;
    int rep;
    if (o <= 1u) rep = 0;                 // words are 0/1 -> int32
    else if (o & 0x80u) rep = 1;          // 0x3F80 halfwords -> bf16
    else if (o & 0x00800000u) rep = 2;    // 0x3F800000 words -> f32
    else rep = 3;                         // 0/1 bytes -> u8/bool
    *maskrep = rep;
  }
}

__device__ __forceinline__ bool maskbit(const void* m, int rep, size_t idx) {
  switch (rep) {
    case 0:  return ((const int*)m)[idx] != 0;
    case 1:  return ((const u16*)m)[idx] != 0;
    case 2:  return ((const u32*)m)[idx] != 0;
    default: return ((const unsigned char*)m)[idx] != 0;
  }
}

// ---------------- weight canonicalization to bf16 ----------------
__global__ __launch_bounds__(256)
void cvt_kernel(const void* __restrict__ src, u16* __restrict__ dst,
                int n8, const int* __restrict__ dtflag) {
  const int i = blockIdx.x * blockDim.x + threadIdx.x;
  if (i >= n8) return;
  if (*dtflag) {
    const float4 a = ((const float4*)src)[i * 2];
    const float4 b = ((const float4*)src)[i * 2 + 1];
    u16 o[8] = {f2bf(a.x), f2bf(a.y), f2bf(a.z), f2bf(a.w),
                f2bf(b.x), f2bf(b.y), f2bf(b.z), f2bf(b.w)};
    *(uint4*)(dst + (size_t)i * 8) = *(const uint4*)o;
  } else {
    ((uint4*)dst)[i] = ((const uint4*)src)[i];
  }
}

// all small 1-D arrays in one launch (biases, gains)
__global__ void cvt_small(const void* s0, u16* d0, const void* s1, u16* d1,
                          const void* s2, u16* d2, const void* s3, u16* d3,
                          const void* s4, u16* d4, const void* s5, u16* d5,
                          const void* s6, u16* d6, const void* s7, u16* d7,
                          const int* __restrict__ dtflag) {
  const int f = *dtflag;
  const void* srcs[8] = {s0, s1, s2, s3, s4, s5, s6, s7};
  u16* dsts[8] = {d0, d1, d2, d3, d4, d5, d6, d7};
  const int ns[8] = {E3, EMB, EMB, EMB, EMB, EMB, MLPD, EMB};
#pragma unroll
  for (int k = 0; k < 8; ++k) {
    for (int idx = threadIdx.x; idx < ns[k]; idx += 256)
      dsts[k][idx] = f ? f2bf(((const float*)srcs[k])[idx])
                       : ((const u16*)srcs[k])[idx];
  }
}

// ------- per-block-row column list builder (stores BYTE offsets into per-head KV plane) -------
__global__ void build_lists(const void* __restrict__ mask, const int* __restrict__ repf,
                            int* __restrict__ lists, int* __restrict__ cnt,
                            unsigned char* __restrict__ diagflag) {
  __shared__ int num;
  const int m = blockIdx.x;
  if (threadIdx.x == 0) num = 0;
  __syncthreads();
  const int rep = *repf;
  const int row0 = m * 8;
  for (int j = threadIdx.x; j < S_LEN; j += 256) {
    int srcrow = (j == row0) ? (row0 + 1) : row0;
    bool bit = maskbit(mask, rep, (size_t)srcrow * S_LEN + j);
    if (j >= row0 && j < row0 + 8) diagflag[j] = bit ? 0 : 1;
    if (bit) {
      int p = atomicAdd(&num, 1);
      if (p < LCAP) lists[m * LCAP + p] = j * 256;   // byte offset within a (b,h) plane
    }
  }
  __syncthreads();
  if (threadIdx.x == 0) cnt[m] = (num < LCAP) ? num : LCAP;
}

// ---------------- LayerNorm (raw f32/bf16 in via flag, bf16 out) ----------------
__global__ __launch_bounds__(256)
void ln_kernel(const void* __restrict__ Xv, const u16* __restrict__ g,
               const u16* __restrict__ be, u16* __restrict__ O,
               const int* __restrict__ inf32) {
  const int wv = threadIdx.x >> 6, ln = threadIdx.x & 63;
  const int row = blockIdx.x * 4 + wv;
  float v[16];
  if (inf32 && *inf32) {
    const float* xr = (const float*)Xv + (size_t)row * EMB;
    float4 a0 = *(const float4*)(xr + ln * 8);
    float4 a1 = *(const float4*)(xr + ln * 8 + 4);
    float4 b0 = *(const float4*)(xr + 512 + ln * 8);
    float4 b1 = *(const float4*)(xr + 512 + ln * 8 + 4);
    v[0]=a0.x; v[1]=a0.y; v[2]=a0.z; v[3]=a0.w; v[4]=a1.x; v[5]=a1.y; v[6]=a1.z; v[7]=a1.w;
    v[8]=b0.x; v[9]=b0.y; v[10]=b0.z; v[11]=b0.w; v[12]=b1.x; v[13]=b1.y; v[14]=b1.z; v[15]=b1.w;
  } else {
    const u16* xr = (const u16*)Xv + (size_t)row * EMB;
    union { uint4 u; u16 s[8]; } p0, p1;
    p0.u = *(const uint4*)(xr + ln * 8);
    p1.u = *(const uint4*)(xr + 512 + ln * 8);
#pragma unroll
    for (int t = 0; t < 8; ++t) { v[t] = bf2f(p0.s[t]); v[8 + t] = bf2f(p1.s[t]); }
  }
  float s = 0.f, sq = 0.f;
#pragma unroll
  for (int t = 0; t < 16; ++t) { s += v[t]; sq += v[t] * v[t]; }
#pragma unroll
  for (int off = 32; off; off >>= 1) { s += __shfl_xor(s, off); sq += __shfl_xor(sq, off); }
  const float mu = s * (1.0f / EMB);
  const float var = sq * (1.0f / EMB) - mu * mu;
  const float rsig = rsqrtf(var + 1e-5f);
  union { uint4 u; u16 s[8]; } g0, g1v, b0, b1v, o0, o1;
  g0.u = *(const uint4*)(g + ln * 8);   g1v.u = *(const uint4*)(g + 512 + ln * 8);
  b0.u = *(const uint4*)(be + ln * 8);  b1v.u = *(const uint4*)(be + 512 + ln * 8);
#pragma unroll
  for (int t = 0; t < 8; ++t) {
    o0.s[t] = f2bf((v[t]     - mu) * rsig * bf2f(g0.s[t])  + bf2f(b0.s[t]));
    o1.s[t] = f2bf((v[8 + t] - mu) * rsig * bf2f(g1v.s[t]) + bf2f(b1v.s[t]));
  }
  u16* orow = O + (size_t)row * EMB;
  *(uint4*)(orow + ln * 8) = o0.u;
  *(uint4*)(orow + 512 + ln * 8) = o1.u;
}

// ---------------- plain GEMM: C = A * B^T + bias, bf16 out (mlp1) ----------------
__global__ __launch_bounds__(256)
void gemm_bt(const u16* __restrict__ A, const u16* __restrict__ B,
             const u16* __restrict__ bias, u16* __restrict__ C,
             int M, int N, int K) {
  __shared__ u16 a_sh[128 * 64];
  __shared__ u16 b_sh[128 * 64];
  const int tid = threadIdx.x;
  const int wv = tid >> 6, ln = tid & 63;
  const int wm = wv & 1, wn = wv >> 1;
  const int tm = blockIdx.y, tn = blockIdx.x;
  const int srow = ln >> 3;
  const int scol = ((ln & 7) ^ srow) * 8;
  const int q = ln >> 4, rr = ln & 15;

  f32x4 acc[4][4] = {};
  const u16* Abase = A + (size_t)(tm * 128) * K;
  const u16* Bbase = B + (size_t)(tn * 128) * K;

  for (int k0 = 0; k0 < K; k0 += 64) {
    __syncthreads();
#pragma unroll
    for (int c = 0; c < 4; ++c) {
      const int chunk = wv * 4 + c;
      const int row = chunk * 8 + srow;
      gl2lds16(Abase + (size_t)row * K + k0 + scol, &a_sh[chunk * 512]);
      gl2lds16(Bbase + (size_t)row * K + k0 + scol, &b_sh[chunk * 512]);
    }
    __syncthreads();
#pragma unroll
    for (int kk = 0; kk < 2; ++kk) {
      const int slot = ((kk * 4 + q) ^ (rr & 7)) * 8;
      s16x8 af[4], bfr[4];
#pragma unroll
      for (int mi = 0; mi < 4; ++mi)
        af[mi] = *(const s16x8*)&a_sh[(wm * 64 + mi * 16 + rr) * 64 + slot];
#pragma unroll
      for (int ni = 0; ni < 4; ++ni)
        bfr[ni] = *(const s16x8*)&b_sh[(wn * 64 + ni * 16 + rr) * 64 + slot];
#pragma unroll
      for (int mi = 0; mi < 4; ++mi)
#pragma unroll
        for (int ni = 0; ni < 4; ++ni)
          acc[mi][ni] = __builtin_amdgcn_mfma_f32_16x16x32_bf16(af[mi], bfr[ni], acc[mi][ni], 0, 0, 0);
    }
  }
#pragma unroll
  for (int ni = 0; ni < 4; ++ni) {
    const int col = tn * 128 + wn * 64 + ni * 16 + rr;
    const float bv = bf2f(bias[col]);
#pragma unroll
    for (int mi = 0; mi < 4; ++mi)
#pragma unroll
      for (int r2 = 0; r2 < 4; ++r2) {
        const int row = tm * 128 + wm * 64 + mi * 16 + q * 4 + r2;
        C[(size_t)row * N + col] = f2bf(acc[mi][ni][r2] + bv);
      }
  }
}

// ---------------- split-K GEMM: partial C = A * B^T over K-half, bf16 partial out ----------------
__global__ __launch_bounds__(256)
void gemm_bt_sk(const u16* __restrict__ A, const u16* __restrict__ B,
                u16* __restrict__ P0, u16* __restrict__ P1,
                int M, int N, int K) {
  __shared__ u16 a_sh[128 * 64];
  __shared__ u16 b_sh[128 * 64];
  const int tid = threadIdx.x;
  const int wv = tid >> 6, ln = tid & 63;
  const int wm = wv & 1, wn = wv >> 1;
  const int tm = blockIdx.y, tn = blockIdx.x, kz = blockIdx.z;
  const int Kh = K >> 1;
  const int koff = kz * Kh;
  const int srow = ln >> 3;
  const int scol = ((ln & 7) ^ srow) * 8;
  const int q = ln >> 4, rr = ln & 15;

  f32x4 acc[4][4] = {};
  const u16* Abase = A + (size_t)(tm * 128) * K + koff;
  const u16* Bbase = B + (size_t)(tn * 128) * K + koff;

  for (int k0 = 0; k0 < Kh; k0 += 64) {
    __syncthreads();
#pragma unroll
    for (int c = 0; c < 4; ++c) {
      const int chunk = wv * 4 + c;
      const int row = chunk * 8 + srow;
      gl2lds16(Abase + (size_t)row * K + k0 + scol, &a_sh[chunk * 512]);
      gl2lds16(Bbase + (size_t)row * K + k0 + scol, &b_sh[chunk * 512]);
    }
    __syncthreads();
#pragma unroll
    for (int kk = 0; kk < 2; ++kk) {
      const int slot = ((kk * 4 + q) ^ (rr & 7)) * 8;
      s16x8 af[4], bfr[4];
#pragma unroll
      for (int mi = 0; mi < 4; ++mi)
        af[mi] = *(const s16x8*)&a_sh[(wm * 64 + mi * 16 + rr) * 64 + slot];
#pragma unroll
      for (int ni = 0; ni < 4; ++ni)
        bfr[ni] = *(const s16x8*)&b_sh[(wn * 64 + ni * 16 + rr) * 64 + slot];
#pragma unroll
      for (int mi = 0; mi < 4; ++mi)
#pragma unroll
        for (int ni = 0; ni < 4; ++ni)
          acc[mi][ni] = __builtin_amdgcn_mfma_f32_16x16x32_bf16(af[mi], bfr[ni], acc[mi][ni], 0, 0, 0);
    }
  }
  u16* P = kz ? P1 : P0;
#pragma unroll
  for (int ni = 0; ni < 4; ++ni) {
    const int col = tn * 128 + wn * 64 + ni * 16 + rr;
#pragma unroll
    for (int mi = 0; mi < 4; ++mi)
#pragma unroll
      for (int r2 = 0; r2 < 4; ++r2) {
        const int row = tm * 128 + wm * 64 + mi * 16 + q * 4 + r2;
        P[(size_t)row * N + col] = f2bf(acc[mi][ni][r2]);
      }
  }
}

// combine: out = P0 + P1 + bias + x   (raw resid dtype + out dtype flagged)
__global__ __launch_bounds__(256)
void combine_kernel(const u16* __restrict__ P0, const u16* __restrict__ P1,
                    const u16* __restrict__ bias, const void* __restrict__ xr,
                    void* __restrict__ Ov, const int* __restrict__ f32io) {
  const int i = blockIdx.x * 256 + threadIdx.x;    // 8-elem group over [NROWS,EMB]
  const int col8 = (i & 127) * 8;                  // column of first elem
  union { uint4 u; u16 s[8]; } a, b, bi;
  a.u = ((const uint4*)P0)[i];
  b.u = ((const uint4*)P1)[i];
  bi.u = *(const uint4*)(bias + col8);
  const int f = *f32io;
  float o[8];
#pragma unroll
  for (int t = 0; t < 8; ++t) o[t] = bf2f(a.s[t]) + bf2f(b.s[t]) + bf2f(bi.s[t]);
  if (f) {
    const float4 x0 = ((const float4*)xr)[i * 2];
    const float4 x1 = ((const float4*)xr)[i * 2 + 1];
    o[0]+=x0.x; o[1]+=x0.y; o[2]+=x0.z; o[3]+=x0.w;
    o[4]+=x1.x; o[5]+=x1.y; o[6]+=x1.z; o[7]+=x1.w;
    float4 r0 = {o[0],o[1],o[2],o[3]}, r1 = {o[4],o[5],o[6],o[7]};
    ((float4*)Ov)[i * 2] = r0;
    ((float4*)Ov)[i * 2 + 1] = r1;
  } else {
    union { uint4 u; u16 s[8]; } xv;
    xv.u = ((const uint4*)xr)[i];
    u16 r[8];
#pragma unroll
    for (int t = 0; t < 8; ++t) r[t] = f2bf(o[t] + bf2f(xv.s[t]));
    ((uint4*)Ov)[i] = *(const uint4*)r;
  }
}

// ---------------- qkv GEMM: epilogue -> Q bf16 plane | per-(b,h) KV f16 planes ----------------
// KV layout: plane bh = b*16+h, per plane S_LEN rows x [K 128B | V 128B] = 512 KB
__global__ __launch_bounds__(256)
void gemm_qkv(const u16* __restrict__ A, const u16* __restrict__ B,
              const u16* __restrict__ bias,
              u16* __restrict__ Qb, u16* __restrict__ KVp,
              int K) {
  __shared__ u16 a_sh[128 * 64];
  __shared__ u16 b_sh[128 * 64];
  const int tid = threadIdx.x;
  const int wv = tid >> 6, ln = tid & 63;
  const int wm = wv & 1, wn = wv >> 1;
  const int tm = blockIdx.y, tn = blockIdx.x;
  const int srow = ln >> 3;
  const int scol = ((ln & 7) ^ srow) * 8;
  const int q = ln >> 4, rr = ln & 15;

  f32x4 acc[4][4] = {};
  const u16* Abase = A + (size_t)(tm * 128) * K;
  const u16* Bbase = B + (size_t)(tn * 128) * K;

  for (int k0 = 0; k0 < K; k0 += 64) {
    __syncthreads();
#pragma unroll
    for (int c = 0; c < 4; ++c) {
      const int chunk = wv * 4 + c;
      const int row = chunk * 8 + srow;
      gl2lds16(Abase + (size_t)row * K + k0 + scol, &a_sh[chunk * 512]);
      gl2lds16(Bbase + (size_t)row * K + k0 + scol, &b_sh[chunk * 512]);
    }
    __syncthreads();
#pragma unroll
    for (int kk = 0; kk < 2; ++kk) {
      const int slot = ((kk * 4 + q) ^ (rr & 7)) * 8;
      s16x8 af[4], bfr[4];
#pragma unroll
      for (int mi = 0; mi < 4; ++mi)
        af[mi] = *(const s16x8*)&a_sh[(wm * 64 + mi * 16 + rr) * 64 + slot];
#pragma unroll
      for (int ni = 0; ni < 4; ++ni)
        bfr[ni] = *(const s16x8*)&b_sh[(wn * 64 + ni * 16 + rr) * 64 + slot];
#pragma unroll
      for (int mi = 0; mi < 4; ++mi)
#pragma unroll
        for (int ni = 0; ni < 4; ++ni)
          acc[mi][ni] = __builtin_amdgcn_mfma_f32_16x16x32_bf16(af[mi], bfr[ni], acc[mi][ni], 0, 0, 0);
    }
  }
  const int third = (tn * 128) >> 10;        // 0=Q, 1=K, 2=V (uniform per block)
#pragma unroll
  for (int ni = 0; ni < 4; ++ni) {
    const int col = tn * 128 + wn * 64 + ni * 16 + rr;
    const int w = col & 1023;
    const float bv = bf2f(bias[col]);
#pragma unroll
    for (int mi = 0; mi < 4; ++mi)
#pragma unroll
      for (int r2 = 0; r2 < 4; ++r2) {
        const int row = tm * 128 + wm * 64 + mi * 16 + q * 4 + r2;
        const float o = acc[mi][ni][r2] + bv;
        if (third == 0) {
          Qb[(size_t)row * 1024 + w] = f2bf(o);
        } else {
          const int hh = w >> 6, d = w & 63;
          const int bq_ = row >> 11, s = row & 2047;      // batch, seq
          KVp[((size_t)(bq_ * NHEAD + hh) * S_LEN + s) * 128 +
              ((third == 1) ? 0 : 64) + d] = f2h(o);
        }
      }
  }
}

// ---------------- N64 GEMM: C = A[M,K]*B[N,K]^T + bias (+resid raw), flagged out ----------------
__global__ __launch_bounds__(256)
void gemm_bt_n64(const u16* __restrict__ A, const u16* __restrict__ B,
                 const u16* __restrict__ bias, const void* __restrict__ resid,
                 void* __restrict__ Cv, int M, int N, int K,
                 const int* __restrict__ residf32, const int* __restrict__ outf32) {
  __shared__ u16 a_sh[128 * 64];
  __shared__ u16 b_sh[64 * 64];
  const int tid = threadIdx.x;
  const int wv = tid >> 6, ln = tid & 63;
  const int wm = wv & 1, wn = wv >> 1;
  const int tm = blockIdx.y, tn = blockIdx.x;
  const int srow = ln >> 3;
  const int scol = ((ln & 7) ^ srow) * 8;
  const int q = ln >> 4, rr = ln & 15;

  f32x4 acc[4][2] = {};
  const u16* Abase = A + (size_t)(tm * 128) * K;
  const u16* Bbase = B + (size_t)(tn * 64) * K;

  for (int k0 = 0; k0 < K; k0 += 64) {
    __syncthreads();
#pragma unroll
    for (int c = 0; c < 4; ++c) {
      const int chunk = wv * 4 + c;
      const int row = chunk * 8 + srow;
      gl2lds16(Abase + (size_t)row * K + k0 + scol, &a_sh[chunk * 512]);
    }
#pragma unroll
    for (int c = 0; c < 2; ++c) {
      const int chunk = wv * 2 + c;                 // 0..7
      const int row = chunk * 8 + srow;             // 0..63
      gl2lds16(Bbase + (size_t)row * K + k0 + scol, &b_sh[chunk * 512]);
    }
    __syncthreads();
#pragma unroll
    for (int kk = 0; kk < 2; ++kk) {
      const int slot = ((kk * 4 + q) ^ (rr & 7)) * 8;
      s16x8 af[4], bfr[2];
#pragma unroll
      for (int mi = 0; mi < 4; ++mi)
        af[mi] = *(const s16x8*)&a_sh[(wm * 64 + mi * 16 + rr) * 64 + slot];
#pragma unroll
      for (int ni = 0; ni < 2; ++ni)
        bfr[ni] = *(const s16x8*)&b_sh[(wn * 32 + ni * 16 + rr) * 64 + slot];
#pragma unroll
      for (int mi = 0; mi < 4; ++mi)
#pragma unroll
        for (int ni = 0; ni < 2; ++ni)
          acc[mi][ni] = __builtin_amdgcn_mfma_f32_16x16x32_bf16(af[mi], bfr[ni], acc[mi][ni], 0, 0, 0);
    }
  }
  const int rf32 = residf32 ? *residf32 : 0;
  const int f32o = outf32 ? *outf32 : 0;
#pragma unroll
  for (int ni = 0; ni < 2; ++ni) {
    const int col = tn * 64 + wn * 32 + ni * 16 + rr;
    const float bv = bf2f(bias[col]);
#pragma unroll
    for (int mi = 0; mi < 4; ++mi)
#pragma unroll
      for (int r2 = 0; r2 < 4; ++r2) {
        const int row = tm * 128 + wm * 64 + mi * 16 + q * 4 + r2;
        const size_t idx = (size_t)row * N + col;
        float o = acc[mi][ni][r2] + bv;
        if (resid)
          o += rf32 ? ((const float*)resid)[idx] : bf2f(((const u16*)resid)[idx]);
        if (f32o) ((float*)Cv)[idx] = o;
        else      ((u16*)Cv)[idx] = f2bf(o);
      }
  }
}

// ------- sparse attention: 4 rows/wave, 8 waves/block (4 block-rows), L2-resident KV -------
// grid g: bh = g & 31 -> g % 8 == bh % 8: all blocks of one (b,h) land on one XCD,
// whose 512 KB plane (x4 planes = 2 MB) stays L2-resident.
__global__ __launch_bounds__(512)
void attn_kernel(const u16* __restrict__ Qb, const u16* __restrict__ KVp,
                 const int* __restrict__ lists,
                 const int* __restrict__ cnt, const unsigned char* __restrict__ diagflag,
                 u16* __restrict__ ctx) {
  __shared__ int list_sh[4][LCAP];
  const int g = blockIdx.x;            // 0..2047
  const int bh = g & 31;               // b*16+h
  const int mq = g >> 5;               // block-row quad (0..63)
  const int b = bh >> 4;
  const int h = bh & 15;
  const int tid = threadIdx.x, wv = tid >> 6, ln = tid & 63;
  const int es = ln >> 3, dc = ln & 7;
  const int lm = wv >> 1;              // which of the 4 block-rows this wave works on
  const int m = mq * 4 + lm;
  const int i0 = m * 8 + (wv & 1) * 4; // this wave owns rows i0..i0+3

  // cooperative load of the 4 column lists
#pragma unroll
  for (int w = 0; w < 4; ++w) {
    const int nw = cnt[mq * 4 + w];
    for (int e = tid; e < nw; e += 512) list_sh[w][e] = lists[(mq * 4 + w) * LCAP + e];
  }
  __syncthreads();

  const int n = cnt[m];

  // 4 query rows, prescaled into exp2 domain
  const float qs = 0.125f * 1.44269504f;
  f16x2 q[4][4];
#pragma unroll
  for (int r = 0; r < 4; ++r) {
    const u16* qrow = Qb + (size_t)(b * S_LEN + i0 + r) * EMB + h * 64 + dc * 8;
    union { uint4 u; u16 s[8]; } qi; qi.u = *(const uint4*)qrow;
#pragma unroll
    for (int t = 0; t < 4; ++t) {
      q[r][t].x = (_Float16)(bf2f(qi.s[2 * t])     * qs);
      q[r][t].y = (_Float16)(bf2f(qi.s[2 * t + 1]) * qs);
    }
  }

  // per-(b,h) plane base; K at s*256 + dc*16, V at +128
  const char* kvb = (const char*)KVp + (size_t)bh * S_LEN * 256;
  const u32 loff = (u32)(dc * 16);

  float sum[4] = {};
  float acc[4][8] = {};

  auto score1 = [&](const uint4& ku, int r) -> float {
    union { uint4 u; f16x2 kk[4]; } K; K.u = ku;
    float s = 0.f;
    if (r == 0) s = fdot2(K.kk[3], q[0][3], fdot2(K.kk[2], q[0][2],
                   fdot2(K.kk[1], q[0][1], fdot2(K.kk[0], q[0][0], 0.f))));
    else if (r == 1) s = fdot2(K.kk[3], q[1][3], fdot2(K.kk[2], q[1][2],
                   fdot2(K.kk[1], q[1][1], fdot2(K.kk[0], q[1][0], 0.f))));
    else if (r == 2) s = fdot2(K.kk[3], q[2][3], fdot2(K.kk[2], q[2][2],
                   fdot2(K.kk[1], q[2][1], fdot2(K.kk[0], q[2][0], 0.f))));
    else s = fdot2(K.kk[3], q[3][3], fdot2(K.kk[2], q[3][2],
                   fdot2(K.kk[1], q[3][1], fdot2(K.kk[0], q[3][0], 0.f))));
    s = red8(s);
    s = fminf(fmaxf(s, -126.f), 126.f);
    return exp2f(s);
  };

  auto PROC = [&](const uint4& ku, const uint4& vu) {
#pragma unroll
    for (int r = 0; r < 4; ++r) {
      const float p = score1(ku, r);
      sum[r] += p;
      fmamix_lo(acc[r][0], vu.x, p); fmamix_hi(acc[r][1], vu.x, p);
      fmamix_lo(acc[r][2], vu.y, p); fmamix_hi(acc[r][3], vu.y, p);
      fmamix_lo(acc[r][4], vu.z, p); fmamix_hi(acc[r][5], vu.z, p);
      fmamix_lo(acc[r][6], vu.w, p); fmamix_hi(acc[r][7], vu.w, p);
    }
  };

  // dropped-diagonal fixup, per owned row (wave-uniform branches)
#pragma unroll
  for (int r = 0; r < 4; ++r) {
    if (diagflag[i0 + r]) {
      const u32 off = (u32)((i0 + r) * 256) + loff;
      const uint4 ku = *(const uint4*)(kvb + off);
      const uint4 vu = *(const uint4*)(kvb + off + 128);
      float p = score1(ku, r);
      p = (es == 0) ? p : 0.f;
      sum[r] += p;
      fmamix_lo(acc[r][0], vu.x, p); fmamix_hi(acc[r][1], vu.x, p);
      fmamix_lo(acc[r][2], vu.y, p); fmamix_hi(acc[r][3], vu.y, p);
      fmamix_lo(acc[r][4], vu.z, p); fmamix_hi(acc[r][5], vu.z, p);
      fmamix_lo(acc[r][6], vu.w, p); fmamix_hi(acc[r][7], vu.w, p);
    }
  }

  int e0 = 0;
  if (n >= 16) {                       // 16-col software pipeline (2 groups in regs)
    uint4 k0, v0, k1, v1;
    {
      const u32 o0 = (u32)list_sh[lm][es] + loff;
      const u32 o1 = (u32)list_sh[lm][8 + es] + loff;
      k0 = *(const uint4*)(kvb + o0); v0 = *(const uint4*)(kvb + o0 + 128);
      k1 = *(const uint4*)(kvb + o1); v1 = *(const uint4*)(kvb + o1 + 128);
    }
    for (; e0 + 32 <= n; e0 += 16) {
      const u32 o0 = (u32)list_sh[lm][e0 + 16 + es] + loff;
      const u32 o1 = (u32)list_sh[lm][e0 + 24 + es] + loff;
      const uint4 nk0 = *(const uint4*)(kvb + o0), nv0 = *(const uint4*)(kvb + o0 + 128);
      const uint4 nk1 = *(const uint4*)(kvb + o1), nv1 = *(const uint4*)(kvb + o1 + 128);
      PROC(k0, v0);
      PROC(k1, v1);
      k0 = nk0; v0 = nv0; k1 = nk1; v1 = nv1;
    }
    PROC(k0, v0);
    PROC(k1, v1);
    e0 += 16;
  }
  for (; e0 + 8 <= n; e0 += 8) {
    const u32 o = (u32)list_sh[lm][e0 + es] + loff;
    const uint4 ku = *(const uint4*)(kvb + o);
    const uint4 vu = *(const uint4*)(kvb + o + 128);
    PROC(ku, vu);
  }
  if (e0 < n) {                        // masked tail
    const int e = e0 + es;
    const bool valid = (e < n);
    const u32 o = (u32)(valid ? list_sh[lm][e] : list_sh[lm][0]) + loff;
    const uint4 ku = *(const uint4*)(kvb + o);
    const uint4 vu = *(const uint4*)(kvb + o + 128);
#pragma unroll
    for (int r = 0; r < 4; ++r) {
      float p = score1(ku, r);
      p = valid ? p : 0.f;
      sum[r] += p;
      fmamix_lo(acc[r][0], vu.x, p); fmamix_hi(acc[r][1], vu.x, p);
      fmamix_lo(acc[r][2], vu.y, p); fmamix_hi(acc[r][3], vu.y, p);
      fmamix_lo(acc[r][4], vu.z, p); fmamix_hi(acc[r][5], vu.z, p);
      fmamix_lo(acc[r][6], vu.w, p); fmamix_hi(acc[r][7], vu.w, p);
    }
  }

  // cross-group reduction (within wave)
#pragma unroll
  for (int off = 8; off < 64; off <<= 1) {
#pragma unroll
    for (int r = 0; r < 4; ++r) {
      sum[r] += __shfl_xor(sum[r], off);
#pragma unroll
      for (int t = 0; t < 8; ++t) acc[r][t] += __shfl_xor(acc[r][t], off);
    }
  }

  if (es == 0) {
#pragma unroll
    for (int r = 0; r < 4; ++r) {
      const float inv = 1.0f / sum[r];
      u16 o[8];
#pragma unroll
      for (int t = 0; t < 8; ++t) o[t] = f2bf(acc[r][t] * inv);
      *(uint4*)(ctx + (size_t)(b * S_LEN + i0 + r) * EMB + h * 64 + dc * 8) = *(const uint4*)o;
    }
  }
}

// ---------------- launch ----------------
extern "C" void kernel_launch(void* const* d_in, const int* in_sizes, int n_in,
                              void* d_out, int out_size, void* d_ws, size_t ws_size,
                              hipStream_t stream) {
  const void* x_raw    = d_in[0];
  const void* mask     = d_in[1];
  const void* wqkv_raw = d_in[2];
  const void* bqkv_raw = d_in[3];
  const void* wout_raw = d_in[4];
  const void* bout_raw = d_in[5];
  const void* g1_raw   = d_in[6];
  const void* be1_raw  = d_in[7];
  const void* g2_raw   = d_in[8];
  const void* be2_raw  = d_in[9];
  const void* w1_raw   = d_in[10];
  const void* b1_raw   = d_in[11];
  const void* w2_raw   = d_in[12];
  const void* b2_raw   = d_in[13];

  char* ws = (char*)d_ws;
  const size_t MB = 1u << 20;
  int* dtflag         = (int*)ws;
  int* maskrep        = (int*)(ws + 64);
  int* cnt            = (int*)(ws + 1024);
  unsigned char* dfl  = (unsigned char*)(ws + 4096);
  int* lists          = (int*)(ws + 8192);               // 640 KB
  u16* R1  = (u16*)(ws + 1 * MB);                        // 8 MB: h -> ctx -> h2 -> mlp2 partial0
  u16* Qb  = (u16*)(ws + 9 * MB);                        // 8 MB: Q bf16 -> out1 -> mlp2 partial1
  u16* KVp = (u16*)(ws + 17 * MB);                       // 16 MB: per-(b,h) K|V f16 planes
  u16* M1  = (u16*)(ws + 17 * MB);                       // 32 MB: mlp1 (overlays KVp, ends 49 MB)
  u16* W   = (u16*)(ws + 49 * MB);                       // 8 MB: weight arena
  char* sm = ws + 57 * MB;
  u16* bq  = (u16*)(sm);
  u16* bo  = (u16*)(sm + 8192);
  u16* g1b = (u16*)(sm + 16384);
  u16* be1b= (u16*)(sm + 24576);
  u16* g2b = (u16*)(sm + 32768);
  u16* be2b= (u16*)(sm + 40960);
  u16* b1b = (u16*)(sm + 49152);
  u16* b2b = (u16*)(sm + 65536);

  detect_flags<<<dim3(1), dim3(256), 0, stream>>>((const u32*)w1_raw, dtflag,
                                                  (const u32*)mask, maskrep);
  build_lists<<<dim3(256), dim3(256), 0, stream>>>(mask, maskrep, lists, cnt, dfl);
  cvt_small<<<dim3(1), dim3(256), 0, stream>>>(
      bqkv_raw, bq, bout_raw, bo, g1_raw, g1b, be1_raw, be1b,
      g2_raw, g2b, be2_raw, be2b, b1_raw, b1b, b2_raw, b2b, dtflag);

  auto cvt = [&](const void* src, u16* dst, int n) {
    const int n8 = n / 8;
    cvt_kernel<<<dim3((n8 + 255) / 256), dim3(256), 0, stream>>>(src, dst, n8, dtflag);
  };

  // h = LN1(x)   (reads raw x, flagged dtype)
  ln_kernel<<<dim3(NROWS / 4), dim3(256), 0, stream>>>(x_raw, g1b, be1b, R1, dtflag);
  // qkv = h @ w_qkv^T + b_qkv -> Q bf16 | per-(b,h) KV f16 planes
  cvt(wqkv_raw, W, E3 * EMB);
  gemm_qkv<<<dim3(E3 / 128, NROWS / 128), dim3(256), 0, stream>>>(
      R1, W, bq, Qb, KVp, EMB);
  // ctx = sparse attention (4 rows/wave, 8 waves/block, XCD-affine grid)
  attn_kernel<<<dim3(2 * NHEAD * 64), dim3(512), 0, stream>>>(
      Qb, KVp, lists, cnt, dfl, R1);
  // out1 = ctx @ w_out^T + b_out + x   (raw resid; out1 -> Qb region)
  cvt(wout_raw, W, EMB * EMB);
  gemm_bt_n64<<<dim3(EMB / 64, NROWS / 128), dim3(256), 0, stream>>>(
      R1, W, bo, x_raw, Qb, NROWS, EMB, EMB, dtflag, nullptr);
  // h2 = LN2(out1)  (out1 in Qb -> h2 in R1; ctx dead)
  ln_kernel<<<dim3(NROWS / 4), dim3(256), 0, stream>>>(Qb, g2b, be2b, R1, nullptr);
  // mlp1 = h2 @ w1^T + bias1  (-> M1, overlays dead KV planes)
  cvt(w1_raw, W, MLPD * EMB);
  gemm_bt<<<dim3(MLPD / 128, NROWS / 128), dim3(256), 0, stream>>>(
      R1, W, b1b, M1, NROWS, MLPD, EMB);
  // mlp2 split-K=2: partials into R1 (h2 dead) and Qb (out1 dead)
  cvt(w2_raw, W, EMB * MLPD);
  gemm_bt_sk<<<dim3(EMB / 128, NROWS / 128, 2), dim3(256), 0, stream>>>(
      M1, W, R1, Qb, NROWS, EMB, MLPD);
  // out = P0 + P1 + bias2 + x   (flagged dtypes)
  combine_kernel<<<dim3(NROWS * EMB / 8 / 256), dim3(256), 0, stream>>>(
      R1, Qb, b2b, x_raw, d_out, dtflag);
}

// Round 8
// 411.614 us; speedup vs baseline: 1.0862x; 1.0862x over previous
//
#include <hip/hip_runtime.h>
#include <cstdint>
#include <cstddef>

typedef unsigned short u16;
typedef unsigned int u32;
typedef unsigned long long u64;
typedef short s16x8 __attribute__((ext_vector_type(8)));
typedef float f32x4 __attribute__((ext_vector_type(4)));
typedef _Float16 f16x4 __attribute__((ext_vector_type(4)));
typedef _Float16 f16x8 __attribute__((ext_vector_type(8)));

#define S_LEN 2048
#define EMB   1024
#define NHEAD 16
#define HD    64
#define E3    3072
#define MLPD  4096
#define NROWS 4096   // B*S
#define LCAP  640    // max kept cols per block-row (mean ~205, sd ~14)

__device__ __forceinline__ float bf2f(u16 v) {
  union { u32 i; float f; } c; c.i = ((u32)v) << 16; return c.f;
}
__device__ __forceinline__ u16 f2bf(float f) {
  union { float f; u32 i; } c; c.f = f;
  u32 x = c.i;
  return (u16)((x + 0x7FFFu + ((x >> 16) & 1u)) >> 16);
}
__device__ __forceinline__ u16 f2h(float f) {
  _Float16 h = (_Float16)f;
  union { _Float16 h; u16 b; } c; c.h = h; return c.b;
}

__device__ __forceinline__ void gl2lds16(const void* g, void* l) {
  __builtin_amdgcn_global_load_lds(
      (__attribute__((address_space(1))) void*)(g),
      (__attribute__((address_space(3))) void*)(l), 16, 0, 0);
}

// ---------------- dtype + mask-representation detection ----------------
__global__ void detect_flags(const u32* __restrict__ w1s, int* __restrict__ dtflag,
                             const u32* __restrict__ mask, int* __restrict__ maskrep) {
  __shared__ int hits[256];
  __shared__ u32 red[256];
  int h = 0; u32 v = 0;
  for (int i = threadIdx.x; i < 4096; i += 256) {
    u32 w = w1s[i];
    if ((w & 0xFFFFu) && (((w >> 7) & 0xFFu) >= 0xC8u)) ++h;
    v |= mask[i];
  }
  hits[threadIdx.x] = h; red[threadIdx.x] = v;
  __syncthreads();
  if (threadIdx.x == 0) {
    int t = 0; u32 o = 0;
    for (int i = 0; i < 256; ++i) { t += hits[i]; o |= red[i]; }
    *dtflag = (t > 8) ? 1 : 0;
    int rep;
    if (o <= 1u) rep = 0;                 // words are 0/1 -> int32
    else if (o & 0x80u) rep = 1;          // 0x3F80 halfwords -> bf16
    else if (o & 0x00800000u) rep = 2;    // 0x3F800000 words -> f32
    else rep = 3;                         // 0/1 bytes -> u8/bool
    *maskrep = rep;
  }
}

__device__ __forceinline__ bool maskbit(const void* m, int rep, size_t idx) {
  switch (rep) {
    case 0:  return ((const int*)m)[idx] != 0;
    case 1:  return ((const u16*)m)[idx] != 0;
    case 2:  return ((const u32*)m)[idx] != 0;
    default: return ((const unsigned char*)m)[idx] != 0;
  }
}

// ---------------- weight canonicalization to bf16 ----------------
__global__ __launch_bounds__(256)
void cvt_kernel(const void* __restrict__ src, u16* __restrict__ dst,
                int n8, const int* __restrict__ dtflag) {
  const int i = blockIdx.x * blockDim.x + threadIdx.x;
  if (i >= n8) return;
  if (*dtflag) {
    const float4 a = ((const float4*)src)[i * 2];
    const float4 b = ((const float4*)src)[i * 2 + 1];
    u16 o[8] = {f2bf(a.x), f2bf(a.y), f2bf(a.z), f2bf(a.w),
                f2bf(b.x), f2bf(b.y), f2bf(b.z), f2bf(b.w)};
    *(uint4*)(dst + (size_t)i * 8) = *(const uint4*)o;
  } else {
    ((uint4*)dst)[i] = ((const uint4*)src)[i];
  }
}

// all small 1-D arrays in one launch (biases, gains)
__global__ void cvt_small(const void* s0, u16* d0, const void* s1, u16* d1,
                          const void* s2, u16* d2, const void* s3, u16* d3,
                          const void* s4, u16* d4, const void* s5, u16* d5,
                          const void* s6, u16* d6, const void* s7, u16* d7,
                          const int* __restrict__ dtflag) {
  const int f = *dtflag;
  const void* srcs[8] = {s0, s1, s2, s3, s4, s5, s6, s7};
  u16* dsts[8] = {d0, d1, d2, d3, d4, d5, d6, d7};
  const int ns[8] = {E3, EMB, EMB, EMB, EMB, EMB, MLPD, EMB};
#pragma unroll
  for (int k = 0; k < 8; ++k) {
    for (int idx = threadIdx.x; idx < ns[k]; idx += 256)
      dsts[k][idx] = f ? f2bf(((const float*)srcs[k])[idx])
                       : ((const u16*)srcs[k])[idx];
  }
}

// ------- per-block-row column list builder (stores BYTE offsets into per-head KV plane) -------
__global__ void build_lists(const void* __restrict__ mask, const int* __restrict__ repf,
                            int* __restrict__ lists, int* __restrict__ cnt,
                            unsigned char* __restrict__ diagflag) {
  __shared__ int num;
  const int m = blockIdx.x;
  if (threadIdx.x == 0) num = 0;
  __syncthreads();
  const int rep = *repf;
  const int row0 = m * 8;
  for (int j = threadIdx.x; j < S_LEN; j += 256) {
    int srcrow = (j == row0) ? (row0 + 1) : row0;
    bool bit = maskbit(mask, rep, (size_t)srcrow * S_LEN + j);
    if (j >= row0 && j < row0 + 8) diagflag[j] = bit ? 0 : 1;
    if (bit) {
      int p = atomicAdd(&num, 1);
      if (p < LCAP) lists[m * LCAP + p] = j * 256;   // byte offset within a (b,h) plane
    }
  }
  __syncthreads();
  if (threadIdx.x == 0) cnt[m] = (num < LCAP) ? num : LCAP;
}

// ---------------- LayerNorm (raw f32/bf16 in via flag, bf16 out) ----------------
__global__ __launch_bounds__(256)
void ln_kernel(const void* __restrict__ Xv, const u16* __restrict__ g,
               const u16* __restrict__ be, u16* __restrict__ O,
               const int* __restrict__ inf32) {
  const int wv = threadIdx.x >> 6, ln = threadIdx.x & 63;
  const int row = blockIdx.x * 4 + wv;
  float v[16];
  if (inf32 && *inf32) {
    const float* xr = (const float*)Xv + (size_t)row * EMB;
    float4 a0 = *(const float4*)(xr + ln * 8);
    float4 a1 = *(const float4*)(xr + ln * 8 + 4);
    float4 b0 = *(const float4*)(xr + 512 + ln * 8);
    float4 b1 = *(const float4*)(xr + 512 + ln * 8 + 4);
    v[0]=a0.x; v[1]=a0.y; v[2]=a0.z; v[3]=a0.w; v[4]=a1.x; v[5]=a1.y; v[6]=a1.z; v[7]=a1.w;
    v[8]=b0.x; v[9]=b0.y; v[10]=b0.z; v[11]=b0.w; v[12]=b1.x; v[13]=b1.y; v[14]=b1.z; v[15]=b1.w;
  } else {
    const u16* xr = (const u16*)Xv + (size_t)row * EMB;
    union { uint4 u; u16 s[8]; } p0, p1;
    p0.u = *(const uint4*)(xr + ln * 8);
    p1.u = *(const uint4*)(xr + 512 + ln * 8);
#pragma unroll
    for (int t = 0; t < 8; ++t) { v[t] = bf2f(p0.s[t]); v[8 + t] = bf2f(p1.s[t]); }
  }
  float s = 0.f, sq = 0.f;
#pragma unroll
  for (int t = 0; t < 16; ++t) { s += v[t]; sq += v[t] * v[t]; }
#pragma unroll
  for (int off = 32; off; off >>= 1) { s += __shfl_xor(s, off); sq += __shfl_xor(sq, off); }
  const float mu = s * (1.0f / EMB);
  const float var = sq * (1.0f / EMB) - mu * mu;
  const float rsig = rsqrtf(var + 1e-5f);
  union { uint4 u; u16 s[8]; } g0, g1v, b0, b1v, o0, o1;
  g0.u = *(const uint4*)(g + ln * 8);   g1v.u = *(const uint4*)(g + 512 + ln * 8);
  b0.u = *(const uint4*)(be + ln * 8);  b1v.u = *(const uint4*)(be + 512 + ln * 8);
#pragma unroll
  for (int t = 0; t < 8; ++t) {
    o0.s[t] = f2bf((v[t]     - mu) * rsig * bf2f(g0.s[t])  + bf2f(b0.s[t]));
    o1.s[t] = f2bf((v[8 + t] - mu) * rsig * bf2f(g1v.s[t]) + bf2f(b1v.s[t]));
  }
  u16* orow = O + (size_t)row * EMB;
  *(uint4*)(orow + ln * 8) = o0.u;
  *(uint4*)(orow + 512 + ln * 8) = o1.u;
}

// ---------------- plain GEMM: C = A * B^T + bias, bf16 out (mlp1) ----------------
__global__ __launch_bounds__(256)
void gemm_bt(const u16* __restrict__ A, const u16* __restrict__ B,
             const u16* __restrict__ bias, u16* __restrict__ C,
             int M, int N, int K) {
  __shared__ u16 a_sh[128 * 64];
  __shared__ u16 b_sh[128 * 64];
  const int tid = threadIdx.x;
  const int wv = tid >> 6, ln = tid & 63;
  const int wm = wv & 1, wn = wv >> 1;
  const int tm = blockIdx.y, tn = blockIdx.x;
  const int srow = ln >> 3;
  const int scol = ((ln & 7) ^ srow) * 8;
  const int q = ln >> 4, rr = ln & 15;

  f32x4 acc[4][4] = {};
  const u16* Abase = A + (size_t)(tm * 128) * K;
  const u16* Bbase = B + (size_t)(tn * 128) * K;

  for (int k0 = 0; k0 < K; k0 += 64) {
    __syncthreads();
#pragma unroll
    for (int c = 0; c < 4; ++c) {
      const int chunk = wv * 4 + c;
      const int row = chunk * 8 + srow;
      gl2lds16(Abase + (size_t)row * K + k0 + scol, &a_sh[chunk * 512]);
      gl2lds16(Bbase + (size_t)row * K + k0 + scol, &b_sh[chunk * 512]);
    }
    __syncthreads();
#pragma unroll
    for (int kk = 0; kk < 2; ++kk) {
      const int slot = ((kk * 4 + q) ^ (rr & 7)) * 8;
      s16x8 af[4], bfr[4];
#pragma unroll
      for (int mi = 0; mi < 4; ++mi)
        af[mi] = *(const s16x8*)&a_sh[(wm * 64 + mi * 16 + rr) * 64 + slot];
#pragma unroll
      for (int ni = 0; ni < 4; ++ni)
        bfr[ni] = *(const s16x8*)&b_sh[(wn * 64 + ni * 16 + rr) * 64 + slot];
#pragma unroll
      for (int mi = 0; mi < 4; ++mi)
#pragma unroll
        for (int ni = 0; ni < 4; ++ni)
          acc[mi][ni] = __builtin_amdgcn_mfma_f32_16x16x32_bf16(af[mi], bfr[ni], acc[mi][ni], 0, 0, 0);
    }
  }
#pragma unroll
  for (int ni = 0; ni < 4; ++ni) {
    const int col = tn * 128 + wn * 64 + ni * 16 + rr;
    const float bv = bf2f(bias[col]);
#pragma unroll
    for (int mi = 0; mi < 4; ++mi)
#pragma unroll
      for (int r2 = 0; r2 < 4; ++r2) {
        const int row = tm * 128 + wm * 64 + mi * 16 + q * 4 + r2;
        C[(size_t)row * N + col] = f2bf(acc[mi][ni][r2] + bv);
      }
  }
}

// ---------------- split-K GEMM: partial C = A * B^T over K-half, bf16 partial out ----------------
__global__ __launch_bounds__(256)
void gemm_bt_sk(const u16* __restrict__ A, const u16* __restrict__ B,
                u16* __restrict__ P0, u16* __restrict__ P1,
                int M, int N, int K) {
  __shared__ u16 a_sh[128 * 64];
  __shared__ u16 b_sh[128 * 64];
  const int tid = threadIdx.x;
  const int wv = tid >> 6, ln = tid & 63;
  const int wm = wv & 1, wn = wv >> 1;
  const int tm = blockIdx.y, tn = blockIdx.x, kz = blockIdx.z;
  const int Kh = K >> 1;
  const int koff = kz * Kh;
  const int srow = ln >> 3;
  const int scol = ((ln & 7) ^ srow) * 8;
  const int q = ln >> 4, rr = ln & 15;

  f32x4 acc[4][4] = {};
  const u16* Abase = A + (size_t)(tm * 128) * K + koff;
  const u16* Bbase = B + (size_t)(tn * 128) * K + koff;

  for (int k0 = 0; k0 < Kh; k0 += 64) {
    __syncthreads();
#pragma unroll
    for (int c = 0; c < 4; ++c) {
      const int chunk = wv * 4 + c;
      const int row = chunk * 8 + srow;
      gl2lds16(Abase + (size_t)row * K + k0 + scol, &a_sh[chunk * 512]);
      gl2lds16(Bbase + (size_t)row * K + k0 + scol, &b_sh[chunk * 512]);
    }
    __syncthreads();
#pragma unroll
    for (int kk = 0; kk < 2; ++kk) {
      const int slot = ((kk * 4 + q) ^ (rr & 7)) * 8;
      s16x8 af[4], bfr[4];
#pragma unroll
      for (int mi = 0; mi < 4; ++mi)
        af[mi] = *(const s16x8*)&a_sh[(wm * 64 + mi * 16 + rr) * 64 + slot];
#pragma unroll
      for (int ni = 0; ni < 4; ++ni)
        bfr[ni] = *(const s16x8*)&b_sh[(wn * 64 + ni * 16 + rr) * 64 + slot];
#pragma unroll
      for (int mi = 0; mi < 4; ++mi)
#pragma unroll
        for (int ni = 0; ni < 4; ++ni)
          acc[mi][ni] = __builtin_amdgcn_mfma_f32_16x16x32_bf16(af[mi], bfr[ni], acc[mi][ni], 0, 0, 0);
    }
  }
  u16* P = kz ? P1 : P0;
#pragma unroll
  for (int ni = 0; ni < 4; ++ni) {
    const int col = tn * 128 + wn * 64 + ni * 16 + rr;
#pragma unroll
    for (int mi = 0; mi < 4; ++mi)
#pragma unroll
      for (int r2 = 0; r2 < 4; ++r2) {
        const int row = tm * 128 + wm * 64 + mi * 16 + q * 4 + r2;
        P[(size_t)row * N + col] = f2bf(acc[mi][ni][r2]);
      }
  }
}

// combine: out = P0 + P1 + bias + x   (raw resid dtype + out dtype flagged)
__global__ __launch_bounds__(256)
void combine_kernel(const u16* __restrict__ P0, const u16* __restrict__ P1,
                    const u16* __restrict__ bias, const void* __restrict__ xr,
                    void* __restrict__ Ov, const int* __restrict__ f32io) {
  const int i = blockIdx.x * 256 + threadIdx.x;    // 8-elem group over [NROWS,EMB]
  const int col8 = (i & 127) * 8;                  // column of first elem
  union { uint4 u; u16 s[8]; } a, b, bi;
  a.u = ((const uint4*)P0)[i];
  b.u = ((const uint4*)P1)[i];
  bi.u = *(const uint4*)(bias + col8);
  const int f = *f32io;
  float o[8];
#pragma unroll
  for (int t = 0; t < 8; ++t) o[t] = bf2f(a.s[t]) + bf2f(b.s[t]) + bf2f(bi.s[t]);
  if (f) {
    const float4 x0 = ((const float4*)xr)[i * 2];
    const float4 x1 = ((const float4*)xr)[i * 2 + 1];
    o[0]+=x0.x; o[1]+=x0.y; o[2]+=x0.z; o[3]+=x0.w;
    o[4]+=x1.x; o[5]+=x1.y; o[6]+=x1.z; o[7]+=x1.w;
    float4 r0 = {o[0],o[1],o[2],o[3]}, r1 = {o[4],o[5],o[6],o[7]};
    ((float4*)Ov)[i * 2] = r0;
    ((float4*)Ov)[i * 2 + 1] = r1;
  } else {
    union { uint4 u; u16 s[8]; } xv;
    xv.u = ((const uint4*)xr)[i];
    u16 r[8];
#pragma unroll
    for (int t = 0; t < 8; ++t) r[t] = f2bf(o[t] + bf2f(xv.s[t]));
    ((uint4*)Ov)[i] = *(const uint4*)r;
  }
}

// ---------------- qkv GEMM: epilogue -> Q f16 (pre-scaled) plane | per-(b,h) KV f16 planes ----
// KV layout: plane bh = b*16+h, per plane S_LEN rows x [K 128B | V 128B] = 512 KB
__global__ __launch_bounds__(256)
void gemm_qkv(const u16* __restrict__ A, const u16* __restrict__ B,
              const u16* __restrict__ bias,
              u16* __restrict__ Qb, u16* __restrict__ KVp,
              int K) {
  __shared__ u16 a_sh[128 * 64];
  __shared__ u16 b_sh[128 * 64];
  const int tid = threadIdx.x;
  const int wv = tid >> 6, ln = tid & 63;
  const int wm = wv & 1, wn = wv >> 1;
  const int tm = blockIdx.y, tn = blockIdx.x;
  const int srow = ln >> 3;
  const int scol = ((ln & 7) ^ srow) * 8;
  const int q = ln >> 4, rr = ln & 15;

  f32x4 acc[4][4] = {};
  const u16* Abase = A + (size_t)(tm * 128) * K;
  const u16* Bbase = B + (size_t)(tn * 128) * K;

  for (int k0 = 0; k0 < K; k0 += 64) {
    __syncthreads();
#pragma unroll
    for (int c = 0; c < 4; ++c) {
      const int chunk = wv * 4 + c;
      const int row = chunk * 8 + srow;
      gl2lds16(Abase + (size_t)row * K + k0 + scol, &a_sh[chunk * 512]);
      gl2lds16(Bbase + (size_t)row * K + k0 + scol, &b_sh[chunk * 512]);
    }
    __syncthreads();
#pragma unroll
    for (int kk = 0; kk < 2; ++kk) {
      const int slot = ((kk * 4 + q) ^ (rr & 7)) * 8;
      s16x8 af[4], bfr[4];
#pragma unroll
      for (int mi = 0; mi < 4; ++mi)
        af[mi] = *(const s16x8*)&a_sh[(wm * 64 + mi * 16 + rr) * 64 + slot];
#pragma unroll
      for (int ni = 0; ni < 4; ++ni)
        bfr[ni] = *(const s16x8*)&b_sh[(wn * 64 + ni * 16 + rr) * 64 + slot];
#pragma unroll
      for (int mi = 0; mi < 4; ++mi)
#pragma unroll
        for (int ni = 0; ni < 4; ++ni)
          acc[mi][ni] = __builtin_amdgcn_mfma_f32_16x16x32_bf16(af[mi], bfr[ni], acc[mi][ni], 0, 0, 0);
    }
  }
  const int third = (tn * 128) >> 10;        // 0=Q, 1=K, 2=V (uniform per block)
  const float QS = 0.125f * 1.44269504f;     // 1/sqrt(D) * log2(e), folded into Q
#pragma unroll
  for (int ni = 0; ni < 4; ++ni) {
    const int col = tn * 128 + wn * 64 + ni * 16 + rr;
    const int w = col & 1023;
    const float bv = bf2f(bias[col]);
#pragma unroll
    for (int mi = 0; mi < 4; ++mi)
#pragma unroll
      for (int r2 = 0; r2 < 4; ++r2) {
        const int row = tm * 128 + wm * 64 + mi * 16 + q * 4 + r2;
        const float o = acc[mi][ni][r2] + bv;
        if (third == 0) {
          Qb[(size_t)row * 1024 + w] = f2h(o * QS);
        } else {
          const int hh = w >> 6, d = w & 63;
          const int bq_ = row >> 11, s = row & 2047;      // batch, seq
          KVp[((size_t)(bq_ * NHEAD + hh) * S_LEN + s) * 128 +
              ((third == 1) ? 0 : 64) + d] = f2h(o);
        }
      }
  }
}

// ---------------- N64 GEMM: C = A[M,K]*B[N,K]^T + bias (+resid raw), flagged out ----------------
__global__ __launch_bounds__(256)
void gemm_bt_n64(const u16* __restrict__ A, const u16* __restrict__ B,
                 const u16* __restrict__ bias, const void* __restrict__ resid,
                 void* __restrict__ Cv, int M, int N, int K,
                 const int* __restrict__ residf32, const int* __restrict__ outf32) {
  __shared__ u16 a_sh[128 * 64];
  __shared__ u16 b_sh[64 * 64];
  const int tid = threadIdx.x;
  const int wv = tid >> 6, ln = tid & 63;
  const int wm = wv & 1, wn = wv >> 1;
  const int tm = blockIdx.y, tn = blockIdx.x;
  const int srow = ln >> 3;
  const int scol = ((ln & 7) ^ srow) * 8;
  const int q = ln >> 4, rr = ln & 15;

  f32x4 acc[4][2] = {};
  const u16* Abase = A + (size_t)(tm * 128) * K;
  const u16* Bbase = B + (size_t)(tn * 64) * K;

  for (int k0 = 0; k0 < K; k0 += 64) {
    __syncthreads();
#pragma unroll
    for (int c = 0; c < 4; ++c) {
      const int chunk = wv * 4 + c;
      const int row = chunk * 8 + srow;
      gl2lds16(Abase + (size_t)row * K + k0 + scol, &a_sh[chunk * 512]);
    }
#pragma unroll
    for (int c = 0; c < 2; ++c) {
      const int chunk = wv * 2 + c;                 // 0..7
      const int row = chunk * 8 + srow;             // 0..63
      gl2lds16(Bbase + (size_t)row * K + k0 + scol, &b_sh[chunk * 512]);
    }
    __syncthreads();
#pragma unroll
    for (int kk = 0; kk < 2; ++kk) {
      const int slot = ((kk * 4 + q) ^ (rr & 7)) * 8;
      s16x8 af[4], bfr[2];
#pragma unroll
      for (int mi = 0; mi < 4; ++mi)
        af[mi] = *(const s16x8*)&a_sh[(wm * 64 + mi * 16 + rr) * 64 + slot];
#pragma unroll
      for (int ni = 0; ni < 2; ++ni)
        bfr[ni] = *(const s16x8*)&b_sh[(wn * 32 + ni * 16 + rr) * 64 + slot];
#pragma unroll
      for (int mi = 0; mi < 4; ++mi)
#pragma unroll
        for (int ni = 0; ni < 2; ++ni)
          acc[mi][ni] = __builtin_amdgcn_mfma_f32_16x16x32_bf16(af[mi], bfr[ni], acc[mi][ni], 0, 0, 0);
    }
  }
  const int rf32 = residf32 ? *residf32 : 0;
  const int f32o = outf32 ? *outf32 : 0;
#pragma unroll
  for (int ni = 0; ni < 2; ++ni) {
    const int col = tn * 64 + wn * 32 + ni * 16 + rr;
    const float bv = bf2f(bias[col]);
#pragma unroll
    for (int mi = 0; mi < 4; ++mi)
#pragma unroll
      for (int r2 = 0; r2 < 4; ++r2) {
        const int row = tm * 128 + wm * 64 + mi * 16 + q * 4 + r2;
        const size_t idx = (size_t)row * N + col;
        float o = acc[mi][ni][r2] + bv;
        if (resid)
          o += rf32 ? ((const float*)resid)[idx] : bf2f(((const u16*)resid)[idx]);
        if (f32o) ((float*)Cv)[idx] = o;
        else      ((u16*)Cv)[idx] = f2bf(o);
      }
  }
}

// ------- sparse attention via MFMA: 1 wave per (b,h,block-row), swapped QK^T -------
// S^T = K_chunk · Q^T via mfma_f32_16x16x32_f16 (K gathered straight into A-frags),
// softmax fully lane-local, PV via mfma_f32_16x16x16f16 with V transposed through LDS.
__global__ __launch_bounds__(256)
void attn_kernel(const u16* __restrict__ Qb, const u16* __restrict__ KVp,
                 const int* __restrict__ lists,
                 const int* __restrict__ cnt, const unsigned char* __restrict__ diagflag,
                 u16* __restrict__ ctx) {
  __shared__ int list_sh[4][LCAP];
  __shared__ uint4 vsh4[4][128];       // per-wave V tile (16 cols x 64 dims f16, swizzled)
  const int g = blockIdx.x;            // 0..2047
  const int bh = g & 31;               // b*16+h  (g%8 XCD affinity for L2-resident planes)
  const int mq = g >> 5;               // block-row quad
  const int b = bh >> 4, h = bh & 15;
  const int tid = threadIdx.x, wv = tid >> 6, ln = tid & 63;
  const int lg = ln >> 4;              // lane group 0..3
  const int dl = ln & 15;              // entry / qrow / dim-offset index
  const int m = mq * 4 + wv;
  const int i0 = m * 8;

  // cooperative load of the 4 column lists
#pragma unroll
  for (int w = 0; w < 4; ++w) {
    const int nw = cnt[mq * 4 + w];
    for (int e = tid; e < nw; e += 256) list_sh[w][e] = lists[(mq * 4 + w) * LCAP + e];
  }
  __syncthreads();

  const int n = cnt[m];
  const u64 du = *(const u64*)(diagflag + i0);   // 8 diag flags, 1 byte each

  // Q fragments (B-operand of S^T): lane: qrow=dl (0-7 real), dims lg*8.. / 32+lg*8..
  f16x8 qb0 = {}, qb1 = {};
  if (dl < 8) {
    const u16* qr = Qb + (size_t)(b * S_LEN + i0 + dl) * EMB + h * 64 + lg * 8;
    union { uint4 u; f16x8 h; } a0, a1;
    a0.u = *(const uint4*)qr;
    a1.u = *(const uint4*)(qr + 32);
    qb0 = a0.h; qb1 = a1.h;
  }

  const char* kvb = (const char*)KVp + (size_t)bh * S_LEN * 256;

  // V LDS tile addressing (conflict-free both sides):
  // hw index I(col, dim) = (dim>>4)*256 + (col&3)*64 + (col>>2)*16 + (dim&15)
  // write (lane: col=dl, dims lg*8+t): uint4 idx = (lg>>1)*32 + (dl&3)*8 + (dl>>2)*2 + (lg&1)
  uint4* vwp = &vsh4[wv][0];
  const int widx = ((lg >> 1) << 5) + ((dl & 3) << 3) + ((dl >> 2) << 1) + (lg & 1);
  // read (lane: col=(lg<<2)+j, dim=dc*16+dl): hw = dc*256 + j*64 + lg*16 + dl
  const u16* vrp = (const u16*)vwp + (lg << 4) + dl;

  float rs = 0.f;
  f32x4 acc[4] = {};

  auto CHUNK = [&](int c0, int mode) {
    // gather: entry e = dl; column byte offset within plane
    int le;
    if (mode == 2) {
      le = (i0 + (dl & 7)) * 256;                 // diagonal columns
    } else {
      const int e = c0 + dl;
      const int idx = (mode == 1 && e >= n) ? 0 : e;
      le = list_sh[wv][idx];
    }
    const char* base = kvb + le + (lg << 4);
    union { uint4 u; f16x8 h; } ka0, ka1;
    ka0.u = *(const uint4*)(base);                // K dims lg*8..+8
    ka1.u = *(const uint4*)(base + 64);           // K dims 32+lg*8..+8
    const uint4 v0 = *(const uint4*)(base + 128); // V dims lg*8..+8
    const uint4 v1 = *(const uint4*)(base + 192); // V dims 32+lg*8..+8

    // S^T = K·Q^T  (C: qrow = dl, column entry = lg*4+r)
    f32x4 st = {};
    st = __builtin_amdgcn_mfma_f32_16x16x32_f16(ka0.h, qb0, st, 0, 0, 0);
    st = __builtin_amdgcn_mfma_f32_16x16x32_f16(ka1.h, qb1, st, 0, 0, 0);

    // stage V (compiler orders ds_write -> ds_read via lgkm, in-order DS pipe)
    vwp[widx] = v0;
    vwp[widx + 64] = v1;

    // softmax (exp2-domain; scale folded into Q) + rowsum, lane-local
    _Float16 ph[4];
#pragma unroll
    for (int r = 0; r < 4; ++r) {
      float s = st[r];
      s = fminf(fmaxf(s, -126.f), 15.f);
      float p = exp2f(s);
      bool keep = true;
      const int e2 = (lg << 2) + r;
      if (mode == 1) keep = (c0 + e2) < n;
      if (mode == 2) keep = (e2 == dl) && (((du >> ((e2 & 7) * 8)) & 1ull) != 0ull);
      p = keep ? p : 0.f;
      ph[r] = (_Float16)p;
      rs += (float)ph[r];
    }
    const f16x4 pa = { ph[0], ph[1], ph[2], ph[3] };   // A-frag of PV, in-lane

    // PV: O += P·V, one 16x16x16 per 16-dim chunk
#pragma unroll
    for (int dc = 0; dc < 4; ++dc) {
      union { u16 s[4]; f16x4 h; } bf;
      bf.s[0] = vrp[dc * 256 +   0];
      bf.s[1] = vrp[dc * 256 +  64];
      bf.s[2] = vrp[dc * 256 + 128];
      bf.s[3] = vrp[dc * 256 + 192];
      acc[dc] = __builtin_amdgcn_mfma_f32_16x16x16f16(pa, bf.h, acc[dc], 0, 0, 0);
    }
  };

  int c0 = 0;
  for (; c0 + 16 <= n; c0 += 16) CHUNK(c0, 0);
  if (c0 < n) CHUNK(c0, 1);
  CHUNK(0, 2);                                    // dropped-diagonal fixup chunk

  // rowsum finalize: every lane gets full sum for qrow = dl
  rs += __shfl_xor(rs, 16);
  rs += __shfl_xor(rs, 32);

  // fetch rowsums for this lane's output rows (qrow = lg*4+r)
  float invs[4];
#pragma unroll
  for (int r = 0; r < 4; ++r) invs[r] = __shfl(rs, (lg << 2) + r);

  if (lg < 2) {                                   // rows 0-7 real
#pragma unroll
    for (int r = 0; r < 4; ++r) {
      const float inv = 1.0f / invs[r];
      u16* orow = ctx + (size_t)(b * S_LEN + i0 + (lg << 2) + r) * EMB + h * 64 + dl;
#pragma unroll
      for (int dc = 0; dc < 4; ++dc)
        orow[dc * 16] = f2bf(acc[dc][r] * inv);
    }
  }
}

// ---------------- launch ----------------
extern "C" void kernel_launch(void* const* d_in, const int* in_sizes, int n_in,
                              void* d_out, int out_size, void* d_ws, size_t ws_size,
                              hipStream_t stream) {
  const void* x_raw    = d_in[0];
  const void* mask     = d_in[1];
  const void* wqkv_raw = d_in[2];
  const void* bqkv_raw = d_in[3];
  const void* wout_raw = d_in[4];
  const void* bout_raw = d_in[5];
  const void* g1_raw   = d_in[6];
  const void* be1_raw  = d_in[7];
  const void* g2_raw   = d_in[8];
  const void* be2_raw  = d_in[9];
  const void* w1_raw   = d_in[10];
  const void* b1_raw   = d_in[11];
  const void* w2_raw   = d_in[12];
  const void* b2_raw   = d_in[13];

  char* ws = (char*)d_ws;
  const size_t MB = 1u << 20;
  int* dtflag         = (int*)ws;
  int* maskrep        = (int*)(ws + 64);
  int* cnt            = (int*)(ws + 1024);
  unsigned char* dfl  = (unsigned char*)(ws + 4096);
  int* lists          = (int*)(ws + 8192);               // 640 KB
  u16* R1  = (u16*)(ws + 1 * MB);                        // 8 MB: h -> ctx -> h2 -> mlp2 partial0
  u16* Qb  = (u16*)(ws + 9 * MB);                        // 8 MB: Q f16 -> out1 -> mlp2 partial1
  u16* KVp = (u16*)(ws + 17 * MB);                       // 16 MB: per-(b,h) K|V f16 planes
  u16* M1  = (u16*)(ws + 17 * MB);                       // 32 MB: mlp1 (overlays KVp, ends 49 MB)
  u16* W   = (u16*)(ws + 49 * MB);                       // 8 MB: weight arena
  char* sm = ws + 57 * MB;
  u16* bq  = (u16*)(sm);
  u16* bo  = (u16*)(sm + 8192);
  u16* g1b = (u16*)(sm + 16384);
  u16* be1b= (u16*)(sm + 24576);
  u16* g2b = (u16*)(sm + 32768);
  u16* be2b= (u16*)(sm + 40960);
  u16* b1b = (u16*)(sm + 49152);
  u16* b2b = (u16*)(sm + 65536);

  detect_flags<<<dim3(1), dim3(256), 0, stream>>>((const u32*)w1_raw, dtflag,
                                                  (const u32*)mask, maskrep);
  build_lists<<<dim3(256), dim3(256), 0, stream>>>(mask, maskrep, lists, cnt, dfl);
  cvt_small<<<dim3(1), dim3(256), 0, stream>>>(
      bqkv_raw, bq, bout_raw, bo, g1_raw, g1b, be1_raw, be1b,
      g2_raw, g2b, be2_raw, be2b, b1_raw, b1b, b2_raw, b2b, dtflag);

  auto cvt = [&](const void* src, u16* dst, int n) {
    const int n8 = n / 8;
    cvt_kernel<<<dim3((n8 + 255) / 256), dim3(256), 0, stream>>>(src, dst, n8, dtflag);
  };

  // h = LN1(x)   (reads raw x, flagged dtype)
  ln_kernel<<<dim3(NROWS / 4), dim3(256), 0, stream>>>(x_raw, g1b, be1b, R1, dtflag);
  // qkv = h @ w_qkv^T + b_qkv -> Q f16 (pre-scaled) | per-(b,h) KV f16 planes
  cvt(wqkv_raw, W, E3 * EMB);
  gemm_qkv<<<dim3(E3 / 128, NROWS / 128), dim3(256), 0, stream>>>(
      R1, W, bq, Qb, KVp, EMB);
  // ctx = sparse attention (MFMA path, 1 wave per block-row, XCD-affine grid)
  attn_kernel<<<dim3(2 * NHEAD * 64), dim3(256), 0, stream>>>(
      Qb, KVp, lists, cnt, dfl, R1);
  // out1 = ctx @ w_out^T + b_out + x   (raw resid; out1 -> Qb region)
  cvt(wout_raw, W, EMB * EMB);
  gemm_bt_n64<<<dim3(EMB / 64, NROWS / 128), dim3(256), 0, stream>>>(
      R1, W, bo, x_raw, Qb, NROWS, EMB, EMB, dtflag, nullptr);
  // h2 = LN2(out1)  (out1 in Qb -> h2 in R1; ctx dead)
  ln_kernel<<<dim3(NROWS / 4), dim3(256), 0, stream>>>(Qb, g2b, be2b, R1, nullptr);
  // mlp1 = h2 @ w1^T + bias1  (-> M1, overlays dead KV planes)
  cvt(w1_raw, W, MLPD * EMB);
  gemm_bt<<<dim3(MLPD / 128, NROWS / 128), dim3(256), 0, stream>>>(
      R1, W, b1b, M1, NROWS, MLPD, EMB);
  // mlp2 split-K=2: partials into R1 (h2 dead) and Qb (out1 dead)
  cvt(w2_raw, W, EMB * MLPD);
  gemm_bt_sk<<<dim3(EMB / 128, NROWS / 128, 2), dim3(256), 0, stream>>>(
      M1, W, R1, Qb, NROWS, EMB, MLPD);
  // out = P0 + P1 + bias2 + x   (flagged dtypes)
  combine_kernel<<<dim3(NROWS * EMB / 8 / 256), dim3(256), 0, stream>>>(
      R1, Qb, b2b, x_raw, d_out, dtflag);
}